// Round 5
// baseline (190.415 us; speedup 1.0000x reference)
//
#include <hip/hip_runtime.h>
#include <hip/hip_bf16.h>
#include <math.h>

// Sparsemax over rows of [N_ROWS, 64] fp32 — one row per thread.
// Michelot fixed-point for the simplex-projection threshold, with the row
// PINNED in VGPRs via opaque inline asm so the compiler cannot rematerialize
// the global loads inside the iteration loop (round 4: VGPR_Count=40 proved
// it was re-reading from L2 every iteration -> latency-bound, 161us).
//
//   tau* = (sum_{x>tau*} x - 1) / |{x>tau*}|
//   init tau0 = max(x) - 1 (lower bound; tau nondecreasing, supports nested)
//   update: tau += (sum(max(0, x - tau)) - 1) / count
//   reference double -1: tau_out = tau* - 1/rho ; out = max(0, x - tau_out)

#define FOR16(OP) OP(0) OP(1) OP(2) OP(3) OP(4) OP(5) OP(6) OP(7) \
                  OP(8) OP(9) OP(10) OP(11) OP(12) OP(13) OP(14) OP(15)

__global__ __launch_bounds__(256, 4) void sparsemax_michelot(
    const float* __restrict__ x, float* __restrict__ out, int n_rows) {
    const int row = blockIdx.x * 256 + threadIdx.x;
    if (row >= n_rows) return;

    const float4* __restrict__ xr = reinterpret_cast<const float4*>(x) + (size_t)row * 16;
    float4* __restrict__ orow = reinterpret_cast<float4*>(out) + (size_t)row * 16;

    // ---- load row into 16 named float4s ----
#define LD(i) float4 a##i = xr[i];
    FOR16(LD)
#undef LD

    // ---- pin all 64 values into VGPRs: the asm "writes" them, so later
    // uses cannot be rematerialized as memory loads ----
#define PIN(i) asm volatile("" : "+v"(a##i.x), "+v"(a##i.y), "+v"(a##i.z), "+v"(a##i.w));
    FOR16(PIN)
#undef PIN

    // ---- row max ----
    float m = -INFINITY;
#define MX(i) m = fmaxf(m, fmaxf(fmaxf(a##i.x, a##i.y), fmaxf(a##i.z, a##i.w)));
    FOR16(MX)
#undef MX

    float tau = m - 1.0f;   // lower bound on tau*
    float cprev = -1.0f;    // impossible count -> at least one iteration
    float cfin = 1.0f;

    for (;;) {
        // s = sum(max(0, a - tau)), c = count(a > tau); 4 parallel accumulators
        float s0 = 0.0f, s1 = 0.0f, s2 = 0.0f, s3 = 0.0f;
        float c0 = 0.0f, c1 = 0.0f, c2 = 0.0f, c3 = 0.0f;
#define ACC(i) {                                        \
        const float dx = a##i.x - tau;                  \
        const float dy = a##i.y - tau;                  \
        const float dz = a##i.z - tau;                  \
        const float dw = a##i.w - tau;                  \
        s0 += fmaxf(dx, 0.0f); c0 += (dx > 0.0f) ? 1.0f : 0.0f; \
        s1 += fmaxf(dy, 0.0f); c1 += (dy > 0.0f) ? 1.0f : 0.0f; \
        s2 += fmaxf(dz, 0.0f); c2 += (dz > 0.0f) ? 1.0f : 0.0f; \
        s3 += fmaxf(dw, 0.0f); c3 += (dw > 0.0f) ? 1.0f : 0.0f; }
        FOR16(ACC)
#undef ACC
        const float s = (s0 + s1) + (s2 + s3);
        const float c = (c0 + c1) + (c2 + c3);
        const bool done = (c == cprev);   // nested supports: same count == same set
        cprev = c;
        cfin = c;
        tau += (s - 1.0f) / c;            // idempotent once converged
        if (__all(done)) break;
    }

    const float tau_out = tau - 1.0f / cfin;   // reference's double -1

    // ---- output: max(0, x - tau_out) ----
#define ST(i) {                                         \
        float4 t;                                       \
        t.x = fmaxf(0.0f, a##i.x - tau_out);            \
        t.y = fmaxf(0.0f, a##i.y - tau_out);            \
        t.z = fmaxf(0.0f, a##i.z - tau_out);            \
        t.w = fmaxf(0.0f, a##i.w - tau_out);            \
        orow[i] = t; }
    FOR16(ST)
#undef ST
}

extern "C" void kernel_launch(void* const* d_in, const int* in_sizes, int n_in,
                              void* d_out, int out_size, void* d_ws, size_t ws_size,
                              hipStream_t stream) {
    const float* x = (const float*)d_in[0];
    float* out = (float*)d_out;
    const int n_rows = in_sizes[0] / 64;

    const int block = 256;
    const int grid = (n_rows + block - 1) / block;  // 4096 for 1M rows
    sparsemax_michelot<<<grid, block, 0, stream>>>(x, out, n_rows);
}

// Round 7
// 152.708 us; speedup vs baseline: 1.2469x; 1.2469x over previous
//
#include <hip/hip_runtime.h>
#include <hip/hip_bf16.h>
#include <math.h>

// Sparsemax over rows of [N_ROWS, 64] fp32 — one row per thread, fp32 resident.
//
// Lessons so far:
//  - r6: fp16 storage FAILS — the reference's double -1 makes the op
//    discontinuous at the support boundary (jump ~1/rho); +-2e-3 perturbation
//    flips rows. Support decisions must be fp32 (~1e-7 perturbation is safe).
//  - r4: fp32 Michelot converges in ~2 effective passes (VALU work ~40us
//    chip-wide) but was latency-bound re-reading the row from L2 each
//    iteration (compiler rematerialized the loads; VGPR_Count=40).
//  - r5: pinning forced residency but the allocator spilled instead
//    (occupancy-targeting ~64 VGPRs despite launch_bounds allowing 128).
//  - fix here: amdgpu_waves_per_eu(1,2) caps the occupancy TARGET at 2
//    waves/EU -> VGPR budget >=256 -> 64 resident fp32 + temps fit spill-free.
//
// Algorithm (Michelot fixed point, z=1 simplex threshold):
//   tau0 = max(x) - 1                      (lower bound on tau*)
//   tau  = (sum_{x>tau} x - 1)/c, repeat; converged when c stops changing
//   reference's double -1: tau_out = tau* - 1/rho ; out = max(0, x - tau_out)

#define FOR16(OP) OP(0) OP(1) OP(2) OP(3) OP(4) OP(5) OP(6) OP(7) \
                  OP(8) OP(9) OP(10) OP(11) OP(12) OP(13) OP(14) OP(15)

__global__ __launch_bounds__(256)
__attribute__((amdgpu_waves_per_eu(1, 2)))
void sparsemax_reg(const float* __restrict__ x, float* __restrict__ out, int n_rows) {
    const int row = blockIdx.x * 256 + threadIdx.x;
    if (row >= n_rows) return;

    const float4* __restrict__ xr = reinterpret_cast<const float4*>(x) + (size_t)row * 16;
    float4* __restrict__ orow = reinterpret_cast<float4*>(out) + (size_t)row * 16;

    // ---- load row into 16 named float4s (64 VGPRs) ----
#define LD(i) float4 a##i = xr[i];
    FOR16(LD)
#undef LD

    // ---- pin: the asm "writes" the values, so later uses cannot be
    // rematerialized as memory loads inside the iteration loop ----
#define PIN(i) asm volatile("" : "+v"(a##i.x), "+v"(a##i.y), "+v"(a##i.z), "+v"(a##i.w));
    FOR16(PIN)
#undef PIN

    // ---- row max ----
    float m = -INFINITY;
#define MX(i) m = fmaxf(m, fmaxf(fmaxf(a##i.x, a##i.y), fmaxf(a##i.z, a##i.w)));
    FOR16(MX)
#undef MX

    float tau = m - 1.0f;   // lower bound on tau*
    int cprev = -1;         // force at least one iteration
    float cfin = 1.0f;

    for (;;) {
        // s = sum(max(0, a - tau)); c = count(a > tau)
        float s0 = 0.0f, s1 = 0.0f;
        int c0 = 0, c1 = 0;
#define ACC(i) {                                                  \
        const float d0 = a##i.x - tau, d1 = a##i.y - tau;         \
        const float d2 = a##i.z - tau, d3 = a##i.w - tau;         \
        s0 += fmaxf(d0, 0.0f); c0 += (d0 > 0.0f);                 \
        s1 += fmaxf(d1, 0.0f); c1 += (d1 > 0.0f);                 \
        s0 += fmaxf(d2, 0.0f); c0 += (d2 > 0.0f);                 \
        s1 += fmaxf(d3, 0.0f); c1 += (d3 > 0.0f); }
        FOR16(ACC)
#undef ACC
        const float s = s0 + s1;
        const int c = c0 + c1;
        const bool done = (c == cprev);   // nested supports: same count == fixed set
        cprev = c;
        const float cf = (float)c;
        cfin = cf;
        tau += (s - 1.0f) / cf;           // idempotent once converged
        if (__all(done)) break;
    }

    const float tau_out = tau - 1.0f / cfin;   // reference's double -1

    // ---- output: max(0, x - tau_out) from the resident registers ----
#define ST(i) {                                         \
        float4 t;                                       \
        t.x = fmaxf(0.0f, a##i.x - tau_out);            \
        t.y = fmaxf(0.0f, a##i.y - tau_out);            \
        t.z = fmaxf(0.0f, a##i.z - tau_out);            \
        t.w = fmaxf(0.0f, a##i.w - tau_out);            \
        orow[i] = t; }
    FOR16(ST)
#undef ST
}

extern "C" void kernel_launch(void* const* d_in, const int* in_sizes, int n_in,
                              void* d_out, int out_size, void* d_ws, size_t ws_size,
                              hipStream_t stream) {
    const float* x = (const float*)d_in[0];
    float* out = (float*)d_out;
    const int n_rows = in_sizes[0] / 64;

    const int block = 256;
    const int grid = (n_rows + block - 1) / block;  // 4096 for 1M rows
    sparsemax_reg<<<grid, block, 0, stream>>>(x, out, n_rows);
}

// Round 8
// 145.613 us; speedup vs baseline: 1.3077x; 1.0487x over previous
//
#include <hip/hip_runtime.h>
#include <hip/hip_bf16.h>
#include <math.h>

// Sparsemax over rows of [N_ROWS, 64] fp32 — TWO THREADS PER ROW.
// Each thread holds a half-row in 8 named float4s (32 VGPRs); total ~55
// VGPRs fits the allocator's default 8-waves/SIMD target, so no spills AND
// full occupancy (r7 showed 64-float residency costs 88 VGPR + occupancy 18%
// -> latency-bound). Pair partials combine via one __shfl_xor(.,1) per
// quantity; fp add is commutative so both lanes get bit-identical tau.
//
// Michelot fixed point (z=1 simplex threshold):
//   tau0 = max(x) - 1                     (lower bound on tau*)
//   tau' = tau + (sum(max(0,x-tau)) - 1)/count ; stop when count fixed
//   (support {x>tau} shrinks monotonically from tau0 -> equal count == fixed)
//   reference's double -1: tau_out = tau* - 1/rho ; out = max(0, x - tau_out)
// Support decisions MUST be fp32 (r6: fp16 flipped boundary rows, jump 1/rho).

#define FOR8(OP) OP(0) OP(1) OP(2) OP(3) OP(4) OP(5) OP(6) OP(7)

__global__ __launch_bounds__(256) void sparsemax_pair(
    const float* __restrict__ x, float* __restrict__ out, int n_rows) {
    const int tid = blockIdx.x * 256 + threadIdx.x;
    const int row = tid >> 1;        // one row per PAIR of lanes
    if (row >= n_rows) return;
    const int half = tid & 1;

    const float4* __restrict__ xr =
        reinterpret_cast<const float4*>(x) + (size_t)row * 16 + half * 8;
    float4* __restrict__ orow =
        reinterpret_cast<float4*>(out) + (size_t)row * 16 + half * 8;

    // ---- load half-row into 8 named float4s (32 VGPRs) ----
#define LD(i) float4 a##i = xr[i];
    FOR8(LD)
#undef LD

    // ---- pin so the loop can't rematerialize loads ----
#define PIN(i) asm volatile("" : "+v"(a##i.x), "+v"(a##i.y), "+v"(a##i.z), "+v"(a##i.w));
    FOR8(PIN)
#undef PIN

    // ---- row max (local 32, then pair-combine) ----
    float m = -INFINITY;
#define MX(i) m = fmaxf(m, fmaxf(fmaxf(a##i.x, a##i.y), fmaxf(a##i.z, a##i.w)));
    FOR8(MX)
#undef MX
    m = fmaxf(m, __shfl_xor(m, 1, 64));

    float tau = m - 1.0f;   // lower bound on tau*
    int cprev = -1;         // force at least one iteration
    float cfin = 1.0f;

    for (;;) {
        float s0 = 0.0f, s1 = 0.0f;
        int c0 = 0, c1 = 0;
#define ACC(i) {                                                  \
        const float d0 = a##i.x - tau, d1 = a##i.y - tau;         \
        const float d2 = a##i.z - tau, d3 = a##i.w - tau;         \
        s0 += fmaxf(d0, 0.0f); c0 += (d0 > 0.0f);                 \
        s1 += fmaxf(d1, 0.0f); c1 += (d1 > 0.0f);                 \
        s0 += fmaxf(d2, 0.0f); c0 += (d2 > 0.0f);                 \
        s1 += fmaxf(d3, 0.0f); c1 += (d3 > 0.0f); }
        FOR8(ACC)
#undef ACC
        float s = s0 + s1;
        int c = c0 + c1;
        // pair-combine: commutative -> identical in both lanes
        s += __shfl_xor(s, 1, 64);
        c += __shfl_xor(c, 1, 64);
        const bool done = (c == cprev);   // nested supports: same count == fixed set
        cprev = c;
        const float cf = (float)c;
        cfin = cf;
        tau += (s - 1.0f) / cf;           // idempotent once converged
        if (__all(done)) break;
    }

    const float tau_out = tau - 1.0f / cfin;   // reference's double -1

    // ---- output: max(0, x - tau_out) ----
#define ST(i) {                                         \
        float4 t;                                       \
        t.x = fmaxf(0.0f, a##i.x - tau_out);            \
        t.y = fmaxf(0.0f, a##i.y - tau_out);            \
        t.z = fmaxf(0.0f, a##i.z - tau_out);            \
        t.w = fmaxf(0.0f, a##i.w - tau_out);            \
        orow[i] = t; }
    FOR8(ST)
#undef ST
}

extern "C" void kernel_launch(void* const* d_in, const int* in_sizes, int n_in,
                              void* d_out, int out_size, void* d_ws, size_t ws_size,
                              hipStream_t stream) {
    const float* x = (const float*)d_in[0];
    float* out = (float*)d_out;
    const int n_rows = in_sizes[0] / 64;

    const int block = 256;                        // 128 rows per block
    const long long n_threads = (long long)n_rows * 2;
    const int grid = (int)((n_threads + block - 1) / block);  // 8192
    sparsemax_pair<<<grid, block, 0, stream>>>(x, out, n_rows);
}

// Round 10
// 102.655 us; speedup vs baseline: 1.8549x; 1.4185x over previous
//
#include <hip/hip_runtime.h>
#include <hip/hip_bf16.h>
#include <math.h>

// Sparsemax over rows of [N_ROWS, 64] fp32 — COALESCED granule distribution.
//
// r8 lesson: 2-threads/row puts consecutive lanes 128B apart -> every VMEM
// instruction touches 64 distinct 64B segments (no lane merging) -> TA/L1
// transaction-bound at ~145us while VALU=32%, HBM=11%.
//
// Here a wave owns 16 rows = 4KB contiguous. Load i reads wavebase + i*1KB +
// lane*16B — minimal 16 segments per instruction. Row 4i+j lives as granule
// a_i of the 16-lane group j; Michelot reductions are commutative, so rows
// reduce across the 16-lane group via DPP butterflies (xor masks {1,2,7,15}
// = quad_perm 0xB1, 0x4E, row_half_mirror, row_mirror — a basis, so all 16
// lanes get bit-identical sums; fp add is commutative). No DS pipe, no LDS.
//
// Michelot fixed point (z=1 simplex threshold), support decisions in fp32
// (r6: fp16 flipped boundary rows — the reference's double -1 makes the op
// discontinuous, jump 1/rho):
//   tau0 = max(x) - 1 ; tau' = tau + (sum(max(0,x-tau)) - 1)/c ;
//   stop when c fixed (nested supports); idempotent after convergence.
//   reference double -1: tau_out = tau* - 1/rho ; out = max(0, x - tau_out)
//
// r9: __builtin_nontemporal_store rejects HIP's float4 class — store via a
// native ext_vector_type(4) alias instead.

typedef float nfloat4 __attribute__((ext_vector_type(4)));

#define FOR4(OP) OP(0) OP(1) OP(2) OP(3)

template <int CTRL>
__device__ __forceinline__ float dpp_bfly(float v) {
    return __int_as_float(__builtin_amdgcn_update_dpp(
        0, __float_as_int(v), CTRL, 0xF, 0xF, false));
}

// full 16-lane sum / max, bit-identical across the 16 lanes
__device__ __forceinline__ float sum16(float v) {
    v += dpp_bfly<0xB1>(v);    // xor 1  (quad_perm [1,0,3,2])
    v += dpp_bfly<0x4E>(v);    // xor 2  (quad_perm [2,3,0,1])
    v += dpp_bfly<0x141>(v);   // xor 7  (row_half_mirror)
    v += dpp_bfly<0x140>(v);   // xor 15 (row_mirror)
    return v;
}
__device__ __forceinline__ float max16(float v) {
    v = fmaxf(v, dpp_bfly<0xB1>(v));
    v = fmaxf(v, dpp_bfly<0x4E>(v));
    v = fmaxf(v, dpp_bfly<0x141>(v));
    v = fmaxf(v, dpp_bfly<0x140>(v));
    return v;
}

__global__ __launch_bounds__(256) void sparsemax_coal(
    const float* __restrict__ x, float* __restrict__ out, int n_rows) {
    const int tid = blockIdx.x * 256 + threadIdx.x;
    const int lane = threadIdx.x & 63;
    const int gwave = tid >> 6;            // global wave id; wave owns 16 rows
    if (gwave * 16 >= n_rows) return;

    const float4* __restrict__ xr = reinterpret_cast<const float4*>(x);
    nfloat4* __restrict__ orow = reinterpret_cast<nfloat4*>(out);
    const size_t base = (size_t)gwave * 256 + lane;   // float4 units; +i*64 per load

    // ---- coalesced load: 4 x 1KB-contiguous dwordx4 ----
#define LD(i) float4 a##i = xr[base + i * 64];
    FOR4(LD)
#undef LD
#define PIN(i) asm volatile("" : "+v"(a##i.x), "+v"(a##i.y), "+v"(a##i.z), "+v"(a##i.w));
    FOR4(PIN)
#undef PIN

    // ---- per-granule row max -> tau0 = max - 1 ----
#define MXI(i)                                                        \
    float tau##i = max16(fmaxf(fmaxf(a##i.x, a##i.y),                 \
                               fmaxf(a##i.z, a##i.w))) - 1.0f;        \
    float cp##i = -1.0f;  /* impossible count: force an iteration */  \
    float rc##i = 1.0f;
    FOR4(MXI)
#undef MXI

    // ---- Michelot iterations (capped; convergence = counts fixed) ----
    for (int it = 0; it < 40; ++it) {
        bool done = true;
#define STEP(i) {                                                     \
        const float d0 = a##i.x - tau##i, d1 = a##i.y - tau##i;       \
        const float d2 = a##i.z - tau##i, d3 = a##i.w - tau##i;       \
        float s = (fmaxf(d0, 0.0f) + fmaxf(d1, 0.0f)) +               \
                  (fmaxf(d2, 0.0f) + fmaxf(d3, 0.0f));                \
        float c = ((d0 > 0.0f ? 1.0f : 0.0f) + (d1 > 0.0f ? 1.0f : 0.0f)) + \
                  ((d2 > 0.0f ? 1.0f : 0.0f) + (d3 > 0.0f ? 1.0f : 0.0f)); \
        s = sum16(s);                                                 \
        c = sum16(c);                                                 \
        done = done && (c == cp##i);                                  \
        cp##i = c;                                                    \
        const float r = __builtin_amdgcn_rcpf(c);                     \
        rc##i = r;                                                    \
        tau##i += (s - 1.0f) * r; }   /* idempotent once converged */
        FOR4(STEP)
#undef STEP
        if (__all(done)) break;
    }

    // ---- output: tau_out = tau - 1/rho (reference's double -1) ----
#define ST(i) {                                                       \
        const float to = tau##i - rc##i;                              \
        nfloat4 t;                                                    \
        t.x = fmaxf(0.0f, a##i.x - to);                               \
        t.y = fmaxf(0.0f, a##i.y - to);                               \
        t.z = fmaxf(0.0f, a##i.z - to);                               \
        t.w = fmaxf(0.0f, a##i.w - to);                               \
        __builtin_nontemporal_store(t, &orow[base + i * 64]); }
    FOR4(ST)
#undef ST
}

extern "C" void kernel_launch(void* const* d_in, const int* in_sizes, int n_in,
                              void* d_out, int out_size, void* d_ws, size_t ws_size,
                              hipStream_t stream) {
    const float* x = (const float*)d_in[0];
    float* out = (float*)d_out;
    const int n_rows = in_sizes[0] / 64;

    const int block = 256;                       // 4 waves = 64 rows per block
    const int rows_per_block = 64;
    const int grid = (n_rows + rows_per_block - 1) / rows_per_block;  // 16384
    sparsemax_coal<<<grid, block, 0, stream>>>(x, out, n_rows);
}